// Round 7
// baseline (1475.299 us; speedup 1.0000x reference)
//
#include <hip/hip_runtime.h>

#define L_HIST 2048
typedef unsigned short ushortT;
typedef __attribute__((ext_vector_type(8))) short bf16x8;
typedef __attribute__((ext_vector_type(4))) short bf16x4;
typedef __attribute__((ext_vector_type(16))) float f32x16;

__device__ __forceinline__ ushortT f2bf(float x) {
  union { float f; unsigned u; } v; v.f = x;
  unsigned r = (v.u + 0x7FFFu + ((v.u >> 16) & 1u)) >> 16;
  return (ushortT)r;
}
__device__ __forceinline__ float bf2f(ushortT h) {
  union { unsigned u; float f; } v; v.u = ((unsigned)h) << 16; return v.f;
}
__device__ __forceinline__ bf16x4 lo4(bf16x8 v) {
  return __builtin_shufflevector(v, v, 0, 1, 2, 3);
}
__device__ __forceinline__ bf16x4 hi4(bf16x8 v) {
  return __builtin_shufflevector(v, v, 4, 5, 6, 7);
}
__device__ __forceinline__ bf16x8 rd8(const ushortT* p) {
  bf16x4 a = *(const bf16x4*)p, b = *(const bf16x4*)(p + 4);
  return __builtin_shufflevector(a, b, 0, 1, 2, 3, 4, 5, 6, 7);
}

// ---------------- ws layout (byte offsets) ----------------------------------
#define NILO 0xFFFFFFFFu
#define PH_(i)  ((unsigned)((i) * 1048576u))
#define PL_(i)  ((unsigned)((i) * 1048576u + 524288u))
#define WC_(c)  ((unsigned)(16u * 1048576u + (c) * 1024u))
#define E1H_(j) ((unsigned)(26u * 1048576u + ((j) - 1u) * 524288u))
#define E1L_(j) ((unsigned)(30u * 1048576u + ((j) - 1u) * 524288u))
#define E2H_(j) ((unsigned)(34u * 1048576u + ((j) - 1u) * 524288u))
#define E2L_(j) ((unsigned)(38u * 1048576u + ((j) - 1u) * 524288u))
#define PF1_(j) ((unsigned)(42u * 1048576u + ((j) - 1u) * 1048576u))
#define PF2_(j) ((unsigned)(50u * 1048576u + ((j) - 1u) * 1048576u))
#define UTH_O   (58u * 1048576u)
#define UTL_O   (60u * 1048576u)
#define QP_O    (62u * 1048576u)
#define RP_O    (64u * 1048576u)
#define SP_O    (64u * 1048576u + 458752u)
#define WV_O    (64u * 1048576u + 458752u + 57344u)
#define CNT_O   (65u * 1048576u)

// ---------------- chain job table (byte-identical to R5 jobs) ---------------
struct DJob { unsigned ph, qh, ql, ch, cl, cf; int mt, tb; };
__device__ const DJob CJ[27] = {
  {PH_(0),PH_(1),PL_(1),PH_(2),PL_(2),NILO,8,0},          // N2
  {PH_(1),PH_(0),PL_(0),PH_(3),PL_(3),NILO,8,64},         // T2
  {WC_(0),PH_(0),PL_(0),WC_(256),NILO,NILO,4,128},        // W1
  {PH_(2),PH_(3),PL_(3),PH_(4),PL_(4),NILO,8,0},          // N4
  {PH_(3),PH_(2),PL_(2),PH_(5),PL_(5),NILO,8,64},         // T4
  {WC_(0),PH_(2),PL_(2),WC_(512),NILO,NILO,8,128},        // W2:4
  {PH_(4),PH_(5),PL_(5),PH_(6),PL_(6),NILO,8,0},          // N8
  {PH_(5),PH_(4),PL_(4),PH_(7),PL_(7),NILO,8,64},         // T8
  {WC_(0),PH_(4),PL_(4),WC_(1024),NILO,NILO,16,128},      // W4:8
  {PH_(6),PH_(7),PL_(7),PH_(8),PL_(8),NILO,8,0},          // N16
  {PH_(7),PH_(6),PL_(6),PH_(9),PL_(9),NILO,8,64},         // T16
  {WC_(0),PH_(6),PL_(6),WC_(2048),NILO,NILO,32,128},      // W8:16
  {PH_(8),PH_(9),PL_(9),PH_(10),PL_(10),NILO,8,0},        // N32
  {PH_(9),PH_(8),PL_(8),E1H_(1),E1L_(1),PF1_(1),8,64},    // T32
  {WC_(0),PH_(8),PL_(8),WC_(4096),NILO,NILO,64,128},      // W16:32
  {PH_(10),E1H_(1),E1L_(1),PH_(11),PL_(11),NILO,8,0},     // N64
  {E1H_(1),PH_(10),PL_(10),E1H_(2),E1L_(2),PF1_(2),8,64}, // T64
  {PH_(11),E1H_(2),E1L_(2),PH_(12),PL_(12),NILO,8,0},     // N128
  {E1H_(1),PH_(11),PL_(11),E1H_(3),E1L_(3),PF1_(3),16,64},// T96,128
  {PH_(12),E1H_(4),E1L_(4),PH_(13),PL_(13),NILO,8,0},     // N256
  {E1H_(1),PH_(12),PL_(12),E1H_(5),NILO,PF1_(5),24,64},   // T160..224
  {E1H_(4),PH_(12),PL_(12),E2H_(1),E2L_(1),PF2_(1),8,256},// T256
  {PH_(13),E2H_(1),E2L_(1),PH_(14),PL_(14),NILO,8,0},     // N512
  {E2H_(1),PH_(13),PL_(13),E2H_(2),E2L_(2),PF2_(2),8,64}, // T512
  {PH_(14),E2H_(2),E2L_(2),PH_(15),PL_(15),NILO,8,0},     // N1024
  {E2H_(1),PH_(14),PL_(14),E2H_(3),NILO,PF2_(3),16,64},   // T768,1024
  {E2H_(1),PH_(15),PL_(15),E2H_(5),NILO,PF2_(5),24,0},    // T1280..1792
};
__device__ const int LJS[11] = {0,3,6,9,12,15,17,19,22,24,26};
__device__ const int LJN[11] = {3,3,3,3,3,2,2,3,2,2,1};
__device__ const int CHT[11] = {160,192,256,384,640,128,192,320,128,192,192};
// ut units: lvl1..10: 70 each; lvl11..13: 100; lvl14: 24  (total 1024)
__device__ const int UTB[15] = {0,0,70,140,210,280,350,420,490,560,630,700,800,900,1000};
__device__ const int NUarr[15] = {466,262,326,454,710,198,262,390,198,262,262,228,128,128,88};

// ---------------- device-wide barrier (G16: device atomics + fences) --------
__device__ __forceinline__ void gbar(unsigned* cnt, unsigned target) {
  __syncthreads();
  if (threadIdx.x == 0) {
    __threadfence();                    // release
    atomicAdd(cnt, 1u);
    while (__hip_atomic_load(cnt, __ATOMIC_RELAXED, __HIP_MEMORY_SCOPE_AGENT) < target)
      __builtin_amdgcn_s_sleep(8);
  }
  __syncthreads();
  __threadfence();                      // acquire (invalidate stale caches)
}

// ---------------- unit workers ----------------------------------------------
__device__ __forceinline__ void chain_tile(char* ws, ushortT* SH, int lvl, int u) {
  DJob J = CJ[LJS[lvl]];
  int jn = LJN[lvl];
  for (int t = 1; t < jn; ++t) {
    DJob J2 = CJ[LJS[lvl] + t];
    if (u >= J2.tb) J = J2;
  }
  int lt = u - J.tb;
  int mtile = lt % J.mt, ntile = lt / J.mt;
  size_t m0 = (size_t)mtile * 64, n0 = (size_t)ntile * 64;
  const ushortT* Ph = (const ushortT*)(ws + J.ph);
  const ushortT* Qh = (const ushortT*)(ws + J.qh);
  const ushortT* Ql = (const ushortT*)(ws + J.ql);
  int tid = threadIdx.x, lane = tid & 63, wave = tid >> 6;
  int wm = (wave & 1) * 32, wn = (wave >> 1) * 32;
  int fr = lane & 31, fk = (lane >> 5) * 8;
  int row = tid >> 2, kp = (tid & 3) * 8;
  ushortT* As = SH;
  ushortT* Bh = SH + 9216;
  ushortT* Bl = SH + 18432;

  const ushortT* pA  = Ph + (m0 + row) * 512 + kp;
  const ushortT* pBh = Qh + (n0 + row) * 512 + kp;
  const ushortT* pBl = Ql + (n0 + row) * 512 + kp;
  bf16x8 rA[4], rBh[4], rBl[4];
#pragma unroll
  for (int s = 0; s < 4; ++s) {
    rA[s]  = *(const bf16x8*)(pA  + s * 32);
    rBh[s] = *(const bf16x8*)(pBh + s * 32);
    rBl[s] = *(const bf16x8*)(pBl + s * 32);
  }
  f32x16 acc;
#pragma unroll
  for (int i = 0; i < 16; ++i) acc[i] = 0.f;

  for (int c = 0; c < 4; ++c) {
#pragma unroll
    for (int s = 0; s < 4; ++s) {
      int o = (s * 64 + row) * 36 + kp;
      *(bf16x4*)&As[o] = lo4(rA[s]);  *(bf16x4*)&As[o + 4] = hi4(rA[s]);
      *(bf16x4*)&Bh[o] = lo4(rBh[s]); *(bf16x4*)&Bh[o + 4] = hi4(rBh[s]);
      *(bf16x4*)&Bl[o] = lo4(rBl[s]); *(bf16x4*)&Bl[o + 4] = hi4(rBl[s]);
    }
    __syncthreads();
    if (c < 3) {
      int off = (c + 1) * 128;
#pragma unroll
      for (int s = 0; s < 4; ++s) {
        rA[s]  = *(const bf16x8*)(pA  + off + s * 32);
        rBh[s] = *(const bf16x8*)(pBh + off + s * 32);
        rBl[s] = *(const bf16x8*)(pBl + off + s * 32);
      }
    }
#pragma unroll
    for (int s = 0; s < 4; ++s)
#pragma unroll
      for (int ks = 0; ks < 32; ks += 16) {
        bf16x8 a  = rd8(&As[(s * 64 + wm + fr) * 36 + ks + fk]);
        bf16x8 bh = rd8(&Bh[(s * 64 + wn + fr) * 36 + ks + fk]);
        bf16x8 bl = rd8(&Bl[(s * 64 + wn + fr) * 36 + ks + fk]);
        acc = __builtin_amdgcn_mfma_f32_32x32x16_bf16(a, bh, acc, 0, 0, 0);
        acc = __builtin_amdgcn_mfma_f32_32x32x16_bf16(a, bl, acc, 0, 0, 0);
      }
    __syncthreads();
  }
  ushortT* Ch = (ushortT*)(ws + J.ch);
  ushortT* Cl = (J.cl != NILO) ? (ushortT*)(ws + J.cl) : nullptr;
  float*   Cf = (J.cf != NILO) ? (float*)(ws + J.cf) : nullptr;
#pragma unroll
  for (int i = 0; i < 16; ++i) {
    int r = wm + (i & 3) + ((i >> 2) << 3) + ((lane >> 5) << 2);
    int cc = wn + (lane & 31);
    float v = acc[i];
    size_t off = (m0 + r) * 512 + (n0 + cc);
    ushortT h = f2bf(v);
    Ch[off] = h;
    if (Cl) Cl[off] = f2bf(v - bf2f(h));
    if (Cf) Cf[off] = v;
  }
}

__device__ __forceinline__ void q_tile(char* ws, ushortT* SH, int u) {
  int z = u & 7, mtile = (u >> 3) & 7, ntile = u >> 6;
  int m0 = mtile * 64, n0 = ntile * 64, k0 = z * 1024;
  const ushortT* WTh = (const ushortT*)(ws + WC_(0));
  const ushortT* UTh = (const ushortT*)(ws + UTH_O);
  const ushortT* UTl = (const ushortT*)(ws + UTL_O);
  float* Qpart = (float*)(ws + QP_O);
  int tid = threadIdx.x, lane = tid & 63, wave = tid >> 6;
  int wm = (wave & 1) * 32, wn = (wave >> 1) * 32;
  int fr = lane & 31, fk = (lane >> 5) * 8;
  int ka = tid & 31, ma = (tid >> 5) * 8;
  int jb = tid >> 2, kb = (tid & 3) * 8;
  ushortT* As = SH;
  ushortT* Bh = SH + 9216;
  ushortT* Bl = SH + 18432;

  const ushortT* pW  = WTh + (size_t)(k0 + ka) * 512 + m0 + ma;
  const ushortT* pUh = UTh + (size_t)(n0 + jb) * 8192 + k0 + kb;
  const ushortT* pUl = UTl + (size_t)(n0 + jb) * 8192 + k0 + kb;
  bf16x8 rW[4], rUh[4], rUl[4];
#pragma unroll
  for (int s = 0; s < 4; ++s) {
    rW[s]  = *(const bf16x8*)(pW + (size_t)(s * 32) * 512);
    rUh[s] = *(const bf16x8*)(pUh + s * 32);
    rUl[s] = *(const bf16x8*)(pUl + s * 32);
  }
  f32x16 acc;
#pragma unroll
  for (int i = 0; i < 16; ++i) acc[i] = 0.f;

  for (int c = 0; c < 8; ++c) {
#pragma unroll
    for (int s = 0; s < 4; ++s) {
#pragma unroll
      for (int e = 0; e < 8; ++e) As[(s * 64 + ma + e) * 36 + ka] = (ushortT)rW[s][e];
      int o = (s * 64 + jb) * 36 + kb;
      *(bf16x4*)&Bh[o] = lo4(rUh[s]); *(bf16x4*)&Bh[o + 4] = hi4(rUh[s]);
      *(bf16x4*)&Bl[o] = lo4(rUl[s]); *(bf16x4*)&Bl[o + 4] = hi4(rUl[s]);
    }
    __syncthreads();
    if (c < 7) {
      int off = (c + 1) * 128;
#pragma unroll
      for (int s = 0; s < 4; ++s) {
        rW[s]  = *(const bf16x8*)(pW + (size_t)(off + s * 32) * 512);
        rUh[s] = *(const bf16x8*)(pUh + off + s * 32);
        rUl[s] = *(const bf16x8*)(pUl + off + s * 32);
      }
    }
#pragma unroll
    for (int s = 0; s < 4; ++s)
#pragma unroll
      for (int ks = 0; ks < 32; ks += 16) {
        bf16x8 a  = rd8(&As[(s * 64 + wm + fr) * 36 + ks + fk]);
        bf16x8 bh = rd8(&Bh[(s * 64 + wn + fr) * 36 + ks + fk]);
        bf16x8 bl = rd8(&Bl[(s * 64 + wn + fr) * 36 + ks + fk]);
        acc = __builtin_amdgcn_mfma_f32_32x32x16_bf16(a, bh, acc, 0, 0, 0);
        acc = __builtin_amdgcn_mfma_f32_32x32x16_bf16(a, bl, acc, 0, 0, 0);
      }
    __syncthreads();
  }
#pragma unroll
  for (int i = 0; i < 16; ++i) {
    int r = wm + (i & 3) + ((i >> 2) << 3) + ((lane >> 5) << 2);
    int cc = wn + (lane & 31);
    Qpart[((size_t)z * 512 + m0 + r) * 128 + n0 + cc] = acc[i];
  }
}

__device__ __forceinline__ void r_unit(char* ws, ushortT* SH, int u) {
  int j1 = u / 4 + 1, dc = u % 4, d0 = dc * 128;
  const float* Pf1 = (const float*)(ws + PF1_(1));
  const float* Qpart = (const float*)(ws + QP_O);
  float* Rpart = (float*)(ws + RP_O);
  float* Qs = (float*)SH;   // 128x8
  for (int i = threadIdx.x; i < 1024; i += 256) {
    int dd = i >> 3, jj = i & 7;
    float s = 0.f;
#pragma unroll
    for (int z = 0; z < 8; ++z)
      s += Qpart[((size_t)z * 512 + d0 + dd) * 128 + j1 + 8 * jj];
    Qs[dd * 8 + jj] = s;
  }
  __syncthreads();
#pragma unroll
  for (int half = 0; half < 2; ++half) {
    int m = threadIdx.x + half * 256;
    float acc[8];
#pragma unroll
    for (int jj = 0; jj < 8; ++jj) acc[jj] = 0.f;
    for (int d = 0; d < 128; ++d) {
      float tv = Pf1[((size_t)(j1 - 1) * 512 + d0 + d) * 512 + m];
      float4 q0 = *(const float4*)&Qs[d * 8];
      float4 q1 = *(const float4*)&Qs[d * 8 + 4];
      acc[0] += tv * q0.x; acc[1] += tv * q0.y; acc[2] += tv * q0.z; acc[3] += tv * q0.w;
      acc[4] += tv * q1.x; acc[5] += tv * q1.y; acc[6] += tv * q1.z; acc[7] += tv * q1.w;
    }
    float* dst = Rpart + (size_t)((j1 - 1) * 4 + dc) * 4096 + m * 8;
#pragma unroll
    for (int jj = 0; jj < 8; ++jj) dst[jj] = acc[jj];
  }
  __syncthreads();
}

__device__ __forceinline__ void s_unit(char* ws, ushortT* SH, int u) {
  int j2 = u / 4 + 1, dc = u % 4, d0 = dc * 128;
  const float* Pf2 = (const float*)(ws + PF2_(1));
  const float* Qpart = (const float*)(ws + QP_O);
  const float* Rpart = (const float*)(ws + RP_O);
  float* Spart = (float*)(ws + SP_O);
  float* Rs = (float*)SH;
  if (threadIdx.x < 128) {
    int dd = threadIdx.x;
    float s = 0.f;
#pragma unroll
    for (int z = 0; z < 8; ++z)
      s += Qpart[((size_t)z * 512 + d0 + dd) * 128 + 8 * j2];
    for (int p = 0; p < 28; ++p)
      s += Rpart[(size_t)p * 4096 + (d0 + dd) * 8 + j2];
    Rs[dd] = s;
  }
  __syncthreads();
#pragma unroll
  for (int half = 0; half < 2; ++half) {
    int m = threadIdx.x + half * 256;
    float acc = 0.f;
    for (int d = 0; d < 128; ++d)
      acc += Pf2[((size_t)(j2 - 1) * 512 + d0 + d) * 512 + m] * Rs[d];
    Spart[(size_t)((j2 - 1) * 4 + dc) * 512 + m] = acc;
  }
  __syncthreads();
}

__device__ __forceinline__ void fin_unit(char* ws, const float* Cmat,
                                         const float* yh, float* out, int u) {
  int p = u * 4 + (threadIdx.x >> 6);
  int lane = threadIdx.x & 63;
  const float* Qpart = (const float*)(ws + QP_O);
  const float* Rpart = (const float*)(ws + RP_O);
  const float* Spart = (const float*)(ws + SP_O);
  float a1 = 0.f, a2 = 0.f;
  for (int t = lane; t < 512; t += 64) {
    float sb = 0.f, qp = 0.f;
#pragma unroll
    for (int z = 0; z < 8; ++z) {
      sb += Qpart[((size_t)z * 512 + t) * 128 + 0];
      qp += Qpart[((size_t)z * 512 + t) * 128 + 64];
    }
    for (int q = 0; q < 28; ++q) {
      sb += Rpart[(size_t)q * 4096 + t * 8];
      sb += Spart[(size_t)q * 512 + t];
    }
    float cv = Cmat[(size_t)p * 512 + t];
    a1 += cv * sb;
    a2 += cv * qp;
  }
  for (int off = 32; off > 0; off >>= 1) {
    a1 += __shfl_down(a1, off);
    a2 += __shfl_down(a2, off);
  }
  if (lane == 0) {
    float ynat = yh[(size_t)(L_HIST - 1) * 256 + p] - a1;
    out[p] = ynat;
    out[256 + p] = ynat + a2;
  }
}

__device__ __forceinline__ void weights_unit(char* ws, ushortT* SH, int v,
    const float* ynh, const float* sigma, const float* phi,
    const float* lambda_e, const float* phi_tilde, float* out) {
  float* wvec = (float*)(ws + WV_O);
  float* w4 = (float*)SH;
  int p = threadIdx.x;
  float val = 0.f;
  if (v == 0) {
    val = ynh[(size_t)(L_HIST - 1) * 256 + p];
    out[512 + p] = 0.f;
  } else if (v <= 16) {
    int i = v - 1;
    float s = 0.f;
    for (int j = 0; j < 24; ++j)
      s += phi_tilde[j * 16 + i] * ynh[(size_t)(L_HIST - 2 - j) * 256 + p];
    val = powf(lambda_e[i], 0.25f) * s;
  } else if (v <= 33) {
    int l = v - 17;
    float s = 0.f;
    for (int k = 0; k < 25; ++k)
      s += phi[k * 17 + l] * ynh[(size_t)(L_HIST - 1 - k) * 256 + p];
    val = powf(sigma[l], 0.25f) * s;
  } else {
    int t = v - 34;
    int i = t / 17, l = t % 17;
    if (p < 48) {
      int m = p;
      int jlo = m - 24; if (jlo < 0) jlo = 0;
      int jhi = m; if (jhi > 23) jhi = 23;
      float s = 0.f;
      for (int j = jlo; j <= jhi; ++j)
        s += phi_tilde[j * 16 + i] * phi[(m - j) * 17 + l];
      w4[p] = s;
    }
    __syncthreads();
    float s = 0.f;
    for (int m = 0; m < 48; ++m)
      s += w4[m] * ynh[(size_t)(L_HIST - 3 - m) * 256 + p];
    val = powf(lambda_e[i], 0.25f) * powf(sigma[l], 0.25f) * s;
    __syncthreads();
  }
  wvec[v * 256 + p] = val;
}

__device__ __forceinline__ void ut_unit(char* ws, int t, const float* Mtens,
                                        const float* Mbar, float* out) {
  const float* wvec = (const float*)(ws + WV_O);
  int n = t & 255, h = t >> 8;
  int lane = threadIdx.x & 63, wid = threadIdx.x >> 6;
  int vs = (306 * h) >> 2, ve = (306 * (h + 1)) >> 2;
  float4 acc = {0.f, 0.f, 0.f, 0.f};
#pragma unroll 4
  for (int v = vs + wid; v < ve; v += 4) {
    const float* mat = (v < 17 ? Mbar : Mtens - 17 * 65536) + (size_t)v * 65536;
    float4 mv = ((const float4*)(mat + (size_t)n * 256))[lane];
    float4 wv = ((const float4*)(wvec + (size_t)v * 256))[lane];
    acc.x += mv.x * wv.x; acc.y += mv.y * wv.y;
    acc.z += mv.z * wv.z; acc.w += mv.w * wv.w;
  }
  float a = (acc.x + acc.y) + (acc.z + acc.w);
  for (int off = 32; off > 0; off >>= 1) a += __shfl_down(a, off);
  if (lane == 0) atomicAdd(&out[512 + n], a);
}

// ---------------- the mega kernel -------------------------------------------
__global__ __launch_bounds__(256, 2) void mega(
    char* ws, const float* Mtens, const float* Mbar, const float* ynh,
    const float* sigv, const float* phiv, const float* lamv, const float* ptv,
    const float* yh, const float* Cmat, float* out) {
  __shared__ ushortT SH[27648];    // 54 KB -> 2 blocks/CU (512 co-resident)
  unsigned* cnt = (unsigned*)(ws + CNT_O);

  for (int lvl = 0; lvl < 15; ++lvl) {
    int nu = NUarr[lvl];
    for (int u = blockIdx.x; u < nu; u += gridDim.x) {
      if (lvl < 11) {
        int ct = CHT[lvl];
        if (u < ct) chain_tile(ws, SH, lvl, u);
        else if (lvl == 0)
          weights_unit(ws, SH, u - ct, ynh, sigv, phiv, lamv, ptv, out);
        else ut_unit(ws, UTB[lvl] + u - ct, Mtens, Mbar, out);
      } else if (lvl == 11) {
        if (u < 128) q_tile(ws, SH, u);
        else ut_unit(ws, UTB[11] + u - 128, Mtens, Mbar, out);
      } else if (lvl == 12) {
        if (u < 28) r_unit(ws, SH, u);
        else ut_unit(ws, UTB[12] + u - 28, Mtens, Mbar, out);
      } else if (lvl == 13) {
        if (u < 28) s_unit(ws, SH, u);
        else ut_unit(ws, UTB[13] + u - 28, Mtens, Mbar, out);
      } else {
        if (u < 64) fin_unit(ws, Cmat, yh, out, u);
        else ut_unit(ws, UTB[14] + u - 64, Mtens, Mbar, out);
      }
    }
    if (lvl < 14) gbar(cnt, (unsigned)(lvl + 1) * gridDim.x);
  }
}

// ---------------- init: split A, split B(hi), pack U, zero barrier ----------
__global__ void init_all(const float* __restrict__ A, const float* __restrict__ B,
                         const float* __restrict__ uh, char* ws) {
  int idx = blockIdx.x * 256 + threadIdx.x;
  if (idx == 0) *(unsigned*)(ws + CNT_O) = 0u;
  ushortT* N1h = (ushortT*)(ws + PH_(0));
  ushortT* N1l = (ushortT*)(ws + PL_(0));
  ushortT* T1h = (ushortT*)(ws + PH_(1));
  ushortT* T1l = (ushortT*)(ws + PL_(1));
  ushortT* WTh = (ushortT*)(ws + WC_(0));
  ushortT* UTh = (ushortT*)(ws + UTH_O);
  ushortT* UTl = (ushortT*)(ws + UTL_O);
  if (idx < 262144) {
    int r = idx >> 9, c = idx & 511;
    float x = A[idx];
    ushortT h = f2bf(x); ushortT l = f2bf(x - bf2f(h));
    N1h[idx] = h; N1l[idx] = l;
    T1h[c * 512 + r] = h; T1l[c * 512 + r] = l;
  } else if (idx < 262144 + 131072) {
    int i2 = idx - 262144;
    int d = i2 >> 8, c = i2 & 255;
    WTh[c * 512 + d] = f2bf(B[i2]);
  } else {
    int i2 = idx - 393216;          // < 128*8192
    int j = i2 >> 13, k = i2 & 8191;
    int tau = k >> 8, c = k & 255;
    float v = 0.f;
    if (j < 64) v = uh[(size_t)(L_HIST - 1 - (32 * j + tau)) * 256 + c];
    else if (j == 64 && tau < 16) v = uh[(size_t)(L_HIST - 1 - tau) * 256 + c];
    ushortT h = f2bf(v);
    UTh[i2] = h; UTl[i2] = f2bf(v - bf2f(h));
  }
}

// ---------------- host orchestration ----------------------------------------
extern "C" void kernel_launch(void* const* d_in, const int* in_sizes, int n_in,
                              void* d_out, int out_size, void* d_ws, size_t ws_size,
                              hipStream_t stream) {
  (void)in_sizes; (void)n_in; (void)out_size; (void)ws_size;
  const float* A   = (const float*)d_in[0];
  const float* B   = (const float*)d_in[1];
  const float* C   = (const float*)d_in[2];
  const float* M   = (const float*)d_in[3];
  const float* Mb  = (const float*)d_in[4];
  const float* sig = (const float*)d_in[5];
  const float* phi = (const float*)d_in[6];
  const float* lam = (const float*)d_in[7];
  const float* pt  = (const float*)d_in[8];
  const float* yh  = (const float*)d_in[9];
  const float* uh  = (const float*)d_in[10];
  const float* ynh = (const float*)d_in[11];
  float* out = (float*)d_out;
  char* base = (char*)d_ws;

  init_all<<<5632, 256, 0, stream>>>(A, B, uh, base);
  mega<<<512, 256, 0, stream>>>(base, M, Mb, ynh, sig, phi, lam, pt, yh, C, out);
}